// Round 4
// baseline (5394.702 us; speedup 1.0000x reference)
//
#include <hip/hip_runtime.h>
#include <math.h>

#define BB 4
#define SS 2048
#define DD 1024
#define SD ((size_t)SS*DD)            // 2,097,152 elems per-batch [S,D]
#define MD ((size_t)BB*SD)            // 8,388,608 total
#define PPB ((size_t)2162688)         // packed P elems per batch: 4096 * 528
// ws: [0,PPB): ln1/P | [PPB,+SD): q/ctx/mid | [+SD,+2SD): k | [+2SD,+3SD): v
//     (k+v regions reused as h in fp32) | flag int at byte offset (PPB+3SD)*2
#define WS_BODY ((PPB + 3*SD) * 2)
#define REQ_WS (WS_BODY + 16)

constexpr float LN_EPS = 1e-6f;

// ---------- bf16 helpers; load scrubs |v|>=2^31 (incl Inf/NaN) to 0 ----------
__device__ __forceinline__ float bfbits2f(unsigned short u){
    if ((u & 0x7F80u) >= 0x4F00u) u = 0;
    return __uint_as_float(((unsigned)u) << 16);
}
__device__ __forceinline__ unsigned short f2bfbits(float f){
    unsigned u = __float_as_uint(f);
    u += 0x7FFFu + ((u >> 16) & 1u);   // RNE
    return (unsigned short)(u >> 16);
}
template<typename TI> struct LD;
template<> struct LD<unsigned short>{
    static __device__ __forceinline__ float s(const unsigned short* p){ return bfbits2f(*p); }
    static __device__ __forceinline__ float4 f4(const unsigned short* p){
        ushort4 u = *(const ushort4*)p;
        return make_float4(bfbits2f(u.x), bfbits2f(u.y), bfbits2f(u.z), bfbits2f(u.w));
    }
};
template<> struct LD<float>{
    static __device__ __forceinline__ float s(const float* p){ return *p; }
    static __device__ __forceinline__ float4 f4(const float* p){ return *(const float4*)p; }
};
__device__ __forceinline__ void st8(unsigned short* p, const float* r){
    *(ushort4*)p     = make_ushort4(f2bfbits(r[0]), f2bfbits(r[1]), f2bfbits(r[2]), f2bfbits(r[3]));
    *(ushort4*)(p+4) = make_ushort4(f2bfbits(r[4]), f2bfbits(r[5]), f2bfbits(r[6]), f2bfbits(r[7]));
}
__device__ __forceinline__ void st8(float* p, const float* r){
    *(float4*)p     = make_float4(r[0],r[1],r[2],r[3]);
    *(float4*)(p+4) = make_float4(r[4],r[5],r[6],r[7]);
}
// packed causal rows: row s keeps cols [0, 64*(g+1)), g = s>>6
__device__ __forceinline__ int rowWidth(int s){ return ((s >> 6) + 1) << 6; }
__device__ __forceinline__ size_t rowOff(int s){
    int g = s >> 6;
    return (size_t)4096 * (size_t)((g * (g + 1)) >> 1) + (size_t)(s & 63) * (size_t)((g + 1) << 6);
}

// ---------- dtype probe: even ushorts of x are values (bf16) or mantissa bits (fp32) ----------
__global__ __launch_bounds__(256)
void probe_kernel(const unsigned short* __restrict__ x, int* __restrict__ flag){
    __shared__ int cnt;
    if (threadIdx.x == 0) cnt = 0;
    __syncthreads();
    unsigned short u = x[2 * threadIdx.x];
    int e = (u >> 7) & 0xFF;
    int sane = ((u & 0x7FFFu) == 0) || (e >= 96 && e <= 140);
    atomicAdd(&cnt, sane);
    __syncthreads();
    if (threadIdx.x == 0) flag[0] = (cnt >= 192) ? 0 : 1;   // 0 = bf16, 1 = fp32
}

// ---------- diagnostic sentinel ----------
__global__ __launch_bounds__(256)
void sentinel_kernel(unsigned short* __restrict__ out, const float val){
    out[(size_t)blockIdx.x * 256 + threadIdx.x] = f2bfbits(val);
}

// ---------- LayerNorm (row of D=1024), ddof=1, eps on std; out bf16 ws ----------
template<typename TX, typename TI, int MODE>
__global__ __launch_bounds__(256)
void ln_kernel(const int* __restrict__ flag, const TX* __restrict__ x,
               const TI* __restrict__ gamma, const TI* __restrict__ beta,
               unsigned short* __restrict__ out)
{
    if (flag[0] != MODE) return;
    __shared__ float red[4];
    const int row = blockIdx.x;
    const TX* xr = x + (size_t)row * DD;
    const int tid = threadIdx.x;
    float v[4]; float s = 0.f;
    #pragma unroll
    for (int i = 0; i < 4; ++i){ v[i] = LD<TX>::s(xr + tid + i*256); s += v[i]; }
    #pragma unroll
    for (int off = 32; off > 0; off >>= 1) s += __shfl_down(s, off, 64);
    if ((tid & 63) == 0) red[tid >> 6] = s;
    __syncthreads();
    const float mean = (red[0]+red[1]+red[2]+red[3]) * (1.0f/DD);
    __syncthreads();
    float q = 0.f;
    #pragma unroll
    for (int i = 0; i < 4; ++i){ float d = v[i]-mean; q += d*d; }
    #pragma unroll
    for (int off = 32; off > 0; off >>= 1) q += __shfl_down(q, off, 64);
    if ((tid & 63) == 0) red[tid >> 6] = q;
    __syncthreads();
    const float var = (red[0]+red[1]+red[2]+red[3]) * (1.0f/(DD-1));
    const float inv = 1.0f/(sqrtf(var) + LN_EPS);
    #pragma unroll
    for (int i = 0; i < 4; ++i){
        int c = tid + i*256;
        out[(size_t)row*DD + c] = f2bfbits(LD<TI>::s(gamma+c)*(v[i]-mean)*inv + LD<TI>::s(beta+c));
    }
}

// ---------- GEMM 128x128x16: out = A(bf16 ws) @ W(TI) + bias(TI) [relu][+resX(TI)][+resF(f32)] ----------
// OUT: 0 = bf16 ws, 1 = f32 ws, 2 = TI (d_out)
template<typename TI, int MODE, bool RELU, bool RES_X, bool RES_F, int OUT>
__global__ __launch_bounds__(256)
void gemm_k(const int* __restrict__ flag,
            const unsigned short* __restrict__ A, const TI* __restrict__ W,
            const TI* __restrict__ bias, const TI* __restrict__ resX,
            const float* __restrict__ resF,
            unsigned short* __restrict__ outB, float* __restrict__ outF, TI* __restrict__ outT,
            const int M, const int N, const int K)
{
    if (flag[0] != MODE) return;
    __shared__ float As[16][128];
    __shared__ float Bs[16][128];
    const int m0 = blockIdx.y * 128;
    const int n0 = blockIdx.x * 128;
    const int tid = threadIdx.x;
    const int tx = tid & 15, ty = tid >> 4;
    float acc[8][8] = {};
    for (int k0 = 0; k0 < K; k0 += 16){
        #pragma unroll
        for (int p = 0; p < 2; ++p){
            int i4 = tid + p*256;
            int m = i4 >> 2, kb = (i4 & 3) << 2;
            float4 av = LD<unsigned short>::f4(A + (size_t)(m0+m)*K + (k0+kb));
            As[kb+0][m]=av.x; As[kb+1][m]=av.y; As[kb+2][m]=av.z; As[kb+3][m]=av.w;
        }
        #pragma unroll
        for (int p = 0; p < 2; ++p){
            int i4 = tid + p*256;
            int k = i4 >> 5, nb = (i4 & 31) << 2;
            float4 wv = LD<TI>::f4(W + (size_t)(k0+k)*N + (n0+nb));
            Bs[k][nb+0]=wv.x; Bs[k][nb+1]=wv.y; Bs[k][nb+2]=wv.z; Bs[k][nb+3]=wv.w;
        }
        __syncthreads();
        #pragma unroll
        for (int kk = 0; kk < 16; ++kk){
            float a[8], b[8];
            *(float4*)&a[0] = *(const float4*)&As[kk][ty*8];
            *(float4*)&a[4] = *(const float4*)&As[kk][ty*8+4];
            *(float4*)&b[0] = *(const float4*)&Bs[kk][tx*8];
            *(float4*)&b[4] = *(const float4*)&Bs[kk][tx*8+4];
            #pragma unroll
            for (int i = 0; i < 8; ++i)
                #pragma unroll
                for (int j = 0; j < 8; ++j)
                    acc[i][j] = fmaf(a[i], b[j], acc[i][j]);
        }
        __syncthreads();
    }
    float bia[8];
    #pragma unroll
    for (int j = 0; j < 8; ++j) bia[j] = LD<TI>::s(bias + n0 + tx*8 + j);
    #pragma unroll
    for (int i = 0; i < 8; ++i){
        const size_t base = (size_t)(m0 + ty*8 + i) * N + n0 + tx*8;
        float r[8];
        #pragma unroll
        for (int j = 0; j < 8; ++j){
            r[j] = acc[i][j] + bia[j];
            if constexpr (RELU) r[j] = fmaxf(r[j], 0.f);
        }
        if constexpr (RES_X){
            float4 u0 = LD<TI>::f4(resX + base);
            float4 u1 = LD<TI>::f4(resX + base + 4);
            r[0]+=u0.x; r[1]+=u0.y; r[2]+=u0.z; r[3]+=u0.w;
            r[4]+=u1.x; r[5]+=u1.y; r[6]+=u1.z; r[7]+=u1.w;
        }
        if constexpr (RES_F){
            float4 f0 = *(const float4*)(resF + base);
            float4 f1 = *(const float4*)(resF + base + 4);
            r[0]+=f0.x; r[1]+=f0.y; r[2]+=f0.z; r[3]+=f0.w;
            r[4]+=f1.x; r[5]+=f1.y; r[6]+=f1.z; r[7]+=f1.w;
        }
        if constexpr (OUT == 0) st8(outB + base, r);
        else if constexpr (OUT == 1) st8(outF + base, r);
        else st8(outT + base, r);
    }
}

// ---------- scores (internal, ungated): packed P[s,t] = q.k * scale ----------
__global__ __launch_bounds__(256)
void scores_packed(const unsigned short* __restrict__ Q, const unsigned short* __restrict__ Km,
                   unsigned short* __restrict__ P, const float scale)
{
    const int s0 = blockIdx.y * 128;
    const int t0 = blockIdx.x * 128;
    if (t0 > s0) return;
    __shared__ float As[16][128];
    __shared__ float Bs[16][128];
    const int tid = threadIdx.x;
    const int tx = tid & 15, ty = tid >> 4;
    float acc[8][8] = {};
    for (int k0 = 0; k0 < DD; k0 += 16){
        #pragma unroll
        for (int p = 0; p < 2; ++p){
            int i4 = tid + p*256;
            int m = i4 >> 2, kb = (i4 & 3) << 2;
            float4 qv = LD<unsigned short>::f4(Q + (size_t)(s0+m)*DD + (k0+kb));
            As[kb+0][m]=qv.x; As[kb+1][m]=qv.y; As[kb+2][m]=qv.z; As[kb+3][m]=qv.w;
            float4 kv = LD<unsigned short>::f4(Km + (size_t)(t0+m)*DD + (k0+kb));
            Bs[kb+0][m]=kv.x; Bs[kb+1][m]=kv.y; Bs[kb+2][m]=kv.z; Bs[kb+3][m]=kv.w;
        }
        __syncthreads();
        #pragma unroll
        for (int kk = 0; kk < 16; ++kk){
            float a[8], b2[8];
            *(float4*)&a[0]  = *(const float4*)&As[kk][ty*8];
            *(float4*)&a[4]  = *(const float4*)&As[kk][ty*8+4];
            *(float4*)&b2[0] = *(const float4*)&Bs[kk][tx*8];
            *(float4*)&b2[4] = *(const float4*)&Bs[kk][tx*8+4];
            #pragma unroll
            for (int i = 0; i < 8; ++i)
                #pragma unroll
                for (int j = 0; j < 8; ++j)
                    acc[i][j] = fmaf(a[i], b2[j], acc[i][j]);
        }
        __syncthreads();
    }
    #pragma unroll
    for (int i = 0; i < 8; ++i){
        const int s = s0 + ty*8 + i;
        const int t = t0 + tx*8;
        if (t < rowWidth(s)){
            float r[8];
            #pragma unroll
            for (int j = 0; j < 8; ++j) r[j] = acc[i][j] * scale;
            st8(P + rowOff(s) + t, r);
        }
    }
}

// ---------- causal softmax over packed rows (internal, ungated) ----------
__global__ __launch_bounds__(256)
void softmax_packed(unsigned short* __restrict__ P)
{
    __shared__ float red[4];
    const int s = blockIdx.x;
    const int width = rowWidth(s);
    unsigned short* r = P + rowOff(s);
    const int tid = threadIdx.x;
    float vals[8];
    float m = -1e30f;
    #pragma unroll
    for (int i = 0; i < 8; ++i){
        int t = tid + i*256;
        float v = -1e30f;
        if (t <= s) v = bfbits2f(r[t]);
        vals[i] = v; m = fmaxf(m, v);
    }
    #pragma unroll
    for (int off = 32; off > 0; off >>= 1) m = fmaxf(m, __shfl_down(m, off, 64));
    if ((tid & 63) == 0) red[tid >> 6] = m;
    __syncthreads();
    const float M4 = fmaxf(fmaxf(red[0],red[1]), fmaxf(red[2],red[3]));
    __syncthreads();
    float ev[8]; float sum = 0.f;
    #pragma unroll
    for (int i = 0; i < 8; ++i){ ev[i] = __expf(vals[i] - M4); sum += ev[i]; }
    #pragma unroll
    for (int off = 32; off > 0; off >>= 1) sum += __shfl_down(sum, off, 64);
    if ((tid & 63) == 0) red[tid >> 6] = sum;
    __syncthreads();
    const float inv = 1.0f / (red[0]+red[1]+red[2]+red[3]);
    #pragma unroll
    for (int i = 0; i < 8; ++i){
        int t = tid + i*256;
        if (t < width) r[t] = f2bfbits(ev[i] * inv);
    }
}

// ---------- ctx = P @ v (internal, ungated), K-loop truncated at diagonal ----------
__global__ __launch_bounds__(256)
void pv_packed(const unsigned short* __restrict__ P, const unsigned short* __restrict__ V,
               unsigned short* __restrict__ C)
{
    const int s0 = blockIdx.y * 128;
    const int n0 = blockIdx.x * 128;
    __shared__ float As[16][128];
    __shared__ float Bs[16][128];
    const int tid = threadIdx.x;
    const int tx = tid & 15, ty = tid >> 4;
    float acc[8][8] = {};
    const int kmax = s0 + 128;
    for (int k0 = 0; k0 < kmax; k0 += 16){
        #pragma unroll
        for (int p2 = 0; p2 < 2; ++p2){
            int i4 = tid + p2*256;
            int m = i4 >> 2, kb = (i4 & 3) << 2;
            const int s = s0 + m;
            float4 f = make_float4(0.f,0.f,0.f,0.f);
            if (k0 + kb < rowWidth(s)) f = LD<unsigned short>::f4(P + rowOff(s) + (k0+kb));
            As[kb+0][m]=f.x; As[kb+1][m]=f.y; As[kb+2][m]=f.z; As[kb+3][m]=f.w;
        }
        #pragma unroll
        for (int p2 = 0; p2 < 2; ++p2){
            int i4 = tid + p2*256;
            int k = i4 >> 5, nb = (i4 & 31) << 2;
            float4 vv = LD<unsigned short>::f4(V + (size_t)(k0+k)*DD + (n0+nb));
            Bs[k][nb+0]=vv.x; Bs[k][nb+1]=vv.y; Bs[k][nb+2]=vv.z; Bs[k][nb+3]=vv.w;
        }
        __syncthreads();
        #pragma unroll
        for (int kk = 0; kk < 16; ++kk){
            float a[8], b2[8];
            *(float4*)&a[0]  = *(const float4*)&As[kk][ty*8];
            *(float4*)&a[4]  = *(const float4*)&As[kk][ty*8+4];
            *(float4*)&b2[0] = *(const float4*)&Bs[kk][tx*8];
            *(float4*)&b2[4] = *(const float4*)&Bs[kk][tx*8+4];
            #pragma unroll
            for (int i = 0; i < 8; ++i)
                #pragma unroll
                for (int j = 0; j < 8; ++j)
                    acc[i][j] = fmaf(a[i], b2[j], acc[i][j]);
        }
        __syncthreads();
    }
    #pragma unroll
    for (int i = 0; i < 8; ++i){
        const size_t base = (size_t)(s0 + ty*8 + i)*DD + n0 + tx*8;
        st8(C + base, acc[i]);
    }
}

extern "C" void kernel_launch(void* const* d_in, const int* in_sizes, int n_in,
                              void* d_out, int out_size, void* d_ws, size_t ws_size,
                              hipStream_t stream)
{
    (void)out_size;
    unsigned short* out_u = (unsigned short*)d_out;
    float*          out_f = (float*)d_out;

    if (n_in < 17){
        sentinel_kernel<<<dim3((unsigned)(MD/256)), dim3(256), 0, stream>>>(out_u, 65536.0f);
        return;
    }
    if (in_sizes[0] != (int)MD){
        sentinel_kernel<<<dim3((unsigned)(MD/256)), dim3(256), 0, stream>>>(out_u, 32768.0f);
        return;
    }
    if (ws_size < (size_t)REQ_WS){
        int k = (int)(ws_size >> 20); if (k > 60) k = 60;
        sentinel_kernel<<<dim3((unsigned)(MD/256)), dim3(256), 0, stream>>>(out_u, ldexpf(1.0f, k));
        return;
    }

    // both-typed views of the inputs
    const unsigned short* in_u[17]; const float* in_f[17];
    for (int i = 0; i < 17; ++i){ in_u[i] = (const unsigned short*)d_in[i]; in_f[i] = (const float*)d_in[i]; }

    unsigned short* wsb = (unsigned short*)d_ws;
    unsigned short* Pp  = wsb;                 // packed P; ln1 shares base (SD <= PPB)
    unsigned short* LN1 = wsb;
    unsigned short* Rq  = wsb + PPB;           // q -> ctx -> mid
    unsigned short* Rk  = Rq + SD;             // k; then h(f32) overlays Rk+Rv
    unsigned short* Rv  = Rk + SD;             // v
    float*          Hf  = (float*)Rk;
    int*            flag = (int*)((char*)d_ws + WS_BODY);

    const dim3 blk(256);
    const dim3 g_gemm(DD/128, SS/128);         // (8,16)
    const dim3 g_sc(SS/128, SS/128);           // (16,16)
    const float scale = 1.0f / sqrtf((float)SS);

    probe_kernel<<<dim3(1), blk, 0, stream>>>(in_u[0], flag);

    for (int b = 0; b < BB; ++b){
        const size_t boff = (size_t)b * SD;
        // 1. ln1(x_b)
        ln_kernel<unsigned short, unsigned short, 0><<<dim3(SS), blk, 0, stream>>>(flag, in_u[0]+boff, in_u[13], in_u[14], LN1);
        ln_kernel<float,          float,          1><<<dim3(SS), blk, 0, stream>>>(flag, in_f[0]+boff, in_f[13], in_f[14], LN1);
        // 2-4. q,k,v
        gemm_k<unsigned short,0,false,false,false,0><<<g_gemm, blk, 0, stream>>>(flag, LN1, in_u[1], in_u[2], (const unsigned short*)nullptr, nullptr, Rq, nullptr, (unsigned short*)nullptr, SS, DD, DD);
        gemm_k<float,         1,false,false,false,0><<<g_gemm, blk, 0, stream>>>(flag, LN1, in_f[1], in_f[2], (const float*)nullptr,          nullptr, Rq, nullptr, (float*)nullptr,          SS, DD, DD);
        gemm_k<unsigned short,0,false,false,false,0><<<g_gemm, blk, 0, stream>>>(flag, LN1, in_u[3], in_u[4], (const unsigned short*)nullptr, nullptr, Rk, nullptr, (unsigned short*)nullptr, SS, DD, DD);
        gemm_k<float,         1,false,false,false,0><<<g_gemm, blk, 0, stream>>>(flag, LN1, in_f[3], in_f[4], (const float*)nullptr,          nullptr, Rk, nullptr, (float*)nullptr,          SS, DD, DD);
        gemm_k<unsigned short,0,false,false,false,0><<<g_gemm, blk, 0, stream>>>(flag, LN1, in_u[5], in_u[6], (const unsigned short*)nullptr, nullptr, Rv, nullptr, (unsigned short*)nullptr, SS, DD, DD);
        gemm_k<float,         1,false,false,false,0><<<g_gemm, blk, 0, stream>>>(flag, LN1, in_f[5], in_f[6], (const float*)nullptr,          nullptr, Rv, nullptr, (float*)nullptr,          SS, DD, DD);
        // 5-7. scores -> softmax -> ctx (internal bf16, ungated)
        scores_packed<<<g_sc, blk, 0, stream>>>(Rq, Rk, Pp, scale);
        softmax_packed<<<dim3(SS), blk, 0, stream>>>(Pp);
        pv_packed<<<g_gemm, blk, 0, stream>>>(Pp, Rv, Rq);
        // 8. h = ctx @ wo + bo + x_b -> f32 (overlays Rk+Rv)
        gemm_k<unsigned short,0,false,true,false,1><<<g_gemm, blk, 0, stream>>>(flag, Rq, in_u[7], in_u[8], in_u[0]+boff, nullptr, nullptr, Hf, (unsigned short*)nullptr, SS, DD, DD);
        gemm_k<float,         1,false,true,false,1><<<g_gemm, blk, 0, stream>>>(flag, Rq, in_f[7], in_f[8], in_f[0]+boff, nullptr, nullptr, Hf, (float*)nullptr,          SS, DD, DD);
        // 9. ln2(h)
        ln_kernel<float, unsigned short, 0><<<dim3(SS), blk, 0, stream>>>(flag, Hf, in_u[15], in_u[16], LN1);
        ln_kernel<float, float,          1><<<dim3(SS), blk, 0, stream>>>(flag, Hf, in_f[15], in_f[16], LN1);
        // 10. mid = relu(ln2 @ w1 + b1)
        gemm_k<unsigned short,0,true,false,false,0><<<g_gemm, blk, 0, stream>>>(flag, LN1, in_u[9], in_u[10], (const unsigned short*)nullptr, nullptr, Rq, nullptr, (unsigned short*)nullptr, SS, DD, DD);
        gemm_k<float,         1,true,false,false,0><<<g_gemm, blk, 0, stream>>>(flag, LN1, in_f[9], in_f[10], (const float*)nullptr,          nullptr, Rq, nullptr, (float*)nullptr,          SS, DD, DD);
        // 11. out_b = mid @ w2 + b2 + h
        gemm_k<unsigned short,0,false,false,true,2><<<g_gemm, blk, 0, stream>>>(flag, Rq, in_u[11], in_u[12], (const unsigned short*)nullptr, Hf, nullptr, nullptr, out_u+boff, SS, DD, DD);
        gemm_k<float,         1,false,false,true,2><<<g_gemm, blk, 0, stream>>>(flag, Rq, in_f[11], in_f[12], (const float*)nullptr,          Hf, nullptr, nullptr, out_f+boff, SS, DD, DD);
    }
}

// Round 5
// 2105.255 us; speedup vs baseline: 2.5625x; 2.5625x over previous
//
#include <hip/hip_runtime.h>
#include <math.h>

#define BB 4
#define SS 2048
#define DD 1024
#define MM (BB*SS)                   // 8192
#define SD ((size_t)SS*DD)           // per-batch [S,D] elems
#define MD ((size_t)MM*DD)           // 8,388,608
#define PPB ((size_t)2162688)        // packed P elems per batch (4096*528)

// slow layout: [0,PPB): ln1/P | [PPB,+SD): q/ctx/mid | [+SD,+2SD): k | [+2SD,+3SD): v (k+v -> h fp32)
#define REQ_SLOW (((PPB + 3*SD) * 2) + 16)
// fast layout (bf16 elems): LN1@0 | Q@MD | K@2MD | V@3MD | P@4MD (4*PPB)
//   ctx -> LN1 region; h fp32 overlays K+V; ln2 -> P region; mid -> Q region
#define REQ_FAST ((4*MD + 4*PPB) * 2)

constexpr float LN_EPS = 1e-6f;

__device__ __forceinline__ unsigned short f2bfbits(float f){
    unsigned u = __float_as_uint(f);
    u += 0x7FFFu + ((u >> 16) & 1u);   // RNE
    return (unsigned short)(u >> 16);
}
__device__ __forceinline__ void unpack8(uint4 u, float* f){
    f[0]=__uint_as_float(u.x<<16); f[1]=__uint_as_float(u.x&0xFFFF0000u);
    f[2]=__uint_as_float(u.y<<16); f[3]=__uint_as_float(u.y&0xFFFF0000u);
    f[4]=__uint_as_float(u.z<<16); f[5]=__uint_as_float(u.z&0xFFFF0000u);
    f[6]=__uint_as_float(u.w<<16); f[7]=__uint_as_float(u.w&0xFFFF0000u);
}
// packed causal rows: row s keeps cols [0, 64*(g+1)), g = s>>6
__device__ __forceinline__ int rowWidth(int s){ return ((s >> 6) + 1) << 6; }
__device__ __forceinline__ size_t rowOff(int s){
    int g = s >> 6;
    return (size_t)4096 * (size_t)((g * (g + 1)) >> 1) + (size_t)(s & 63) * (size_t)((g + 1) << 6);
}

__global__ __launch_bounds__(256)
void sentinel_kernel(float* __restrict__ out, const float val){
    out[(size_t)blockIdx.x * 256 + threadIdx.x] = val;
}

// ---------- LayerNorm: fp32 in -> bf16 ws out. ddof=1 std, eps on std ----------
__global__ __launch_bounds__(256)
void ln_f32(const float* __restrict__ x, const float* __restrict__ gamma,
            const float* __restrict__ beta, unsigned short* __restrict__ out)
{
    __shared__ float red[4];
    const int row = blockIdx.x;
    const int tid = threadIdx.x;
    float4 xv = ((const float4*)(x + (size_t)row*DD))[tid];
    float v[4] = {xv.x, xv.y, xv.z, xv.w};
    float s = v[0]+v[1]+v[2]+v[3];
    #pragma unroll
    for (int off = 32; off > 0; off >>= 1) s += __shfl_down(s, off, 64);
    if ((tid & 63) == 0) red[tid >> 6] = s;
    __syncthreads();
    const float mean = (red[0]+red[1]+red[2]+red[3]) * (1.0f/DD);
    __syncthreads();
    float q = 0.f;
    #pragma unroll
    for (int i = 0; i < 4; ++i){ float d = v[i]-mean; q += d*d; }
    #pragma unroll
    for (int off = 32; off > 0; off >>= 1) q += __shfl_down(q, off, 64);
    if ((tid & 63) == 0) red[tid >> 6] = q;
    __syncthreads();
    const float var = (red[0]+red[1]+red[2]+red[3]) * (1.0f/(DD-1));
    const float inv = 1.0f/(sqrtf(var) + LN_EPS);
    float4 g4 = ((const float4*)gamma)[tid];
    float4 b4 = ((const float4*)beta)[tid];
    ushort4 o;
    o.x = f2bfbits(g4.x*(v[0]-mean)*inv + b4.x);
    o.y = f2bfbits(g4.y*(v[1]-mean)*inv + b4.y);
    o.z = f2bfbits(g4.z*(v[2]-mean)*inv + b4.z);
    o.w = f2bfbits(g4.w*(v[3]-mean)*inv + b4.w);
    ((ushort4*)(out + (size_t)row*DD))[tid] = o;
}

// ---------- GEMM 128x128x16: out = A(bf16 ws)[M,K] @ W(f32)[K,N] + bias [relu][+resF(f32)] ----------
// micro-tile: rows ty*8+{0..7}, cols tx*4+{0..3} and 64+tx*4+{0..3}  (bank-friendly)
template<bool RELU, bool RES, bool OUTF>
__global__ __launch_bounds__(256)
void gemm_ws(const unsigned short* __restrict__ A, const float* __restrict__ W,
             const float* __restrict__ bias, const float* __restrict__ resF,
             unsigned short* __restrict__ outB, float* __restrict__ outF,
             const int M, const int N, const int K)
{
    __shared__ float As[16][132];
    __shared__ float Bs[16][132];
    const int m0 = blockIdx.y * 128, n0 = blockIdx.x * 128;
    const int tid = threadIdx.x, tx = tid & 15, ty = tid >> 4;
    const int am = tid >> 1, akb = (tid & 1) * 8;     // A staging: 128m x 16k, 8 k per thread
    float acc[8][8] = {};
    for (int k0 = 0; k0 < K; k0 += 16){
        uint4 ua = *(const uint4*)(A + (size_t)(m0+am)*K + (k0+akb));
        float fa[8]; unpack8(ua, fa);
        #pragma unroll
        for (int j = 0; j < 8; ++j) As[akb+j][am] = fa[j];
        #pragma unroll
        for (int p = 0; p < 2; ++p){
            int i4 = tid + p*256;
            int k = i4 >> 5, nb = (i4 & 31) << 2;
            *(float4*)&Bs[k][nb] = *(const float4*)(W + (size_t)(k0+k)*N + (n0+nb));
        }
        __syncthreads();
        #pragma unroll
        for (int kk = 0; kk < 16; ++kk){
            float a[8], b[8];
            *(float4*)&a[0] = *(const float4*)&As[kk][ty*8];
            *(float4*)&a[4] = *(const float4*)&As[kk][ty*8+4];
            *(float4*)&b[0] = *(const float4*)&Bs[kk][tx*4];
            *(float4*)&b[4] = *(const float4*)&Bs[kk][64+tx*4];
            #pragma unroll
            for (int i = 0; i < 8; ++i)
                #pragma unroll
                for (int j = 0; j < 8; ++j)
                    acc[i][j] = fmaf(a[i], b[j], acc[i][j]);
        }
        __syncthreads();
    }
    float bia[8];
    #pragma unroll
    for (int j = 0; j < 4; ++j){ bia[j] = bias[n0+tx*4+j]; bia[4+j] = bias[n0+64+tx*4+j]; }
    #pragma unroll
    for (int i = 0; i < 8; ++i){
        const size_t base0 = (size_t)(m0 + ty*8 + i) * N + n0 + tx*4;
        const size_t base1 = base0 + 64;
        float r[8];
        #pragma unroll
        for (int j = 0; j < 8; ++j){
            r[j] = acc[i][j] + bia[j];
            if constexpr (RELU) r[j] = fmaxf(r[j], 0.f);
        }
        if constexpr (RES){
            float4 f0 = *(const float4*)(resF + base0);
            float4 f1 = *(const float4*)(resF + base1);
            r[0]+=f0.x; r[1]+=f0.y; r[2]+=f0.z; r[3]+=f0.w;
            r[4]+=f1.x; r[5]+=f1.y; r[6]+=f1.z; r[7]+=f1.w;
        }
        if constexpr (OUTF){
            *(float4*)(outF + base0) = make_float4(r[0],r[1],r[2],r[3]);
            *(float4*)(outF + base1) = make_float4(r[4],r[5],r[6],r[7]);
        } else {
            *(ushort4*)(outB + base0) = make_ushort4(f2bfbits(r[0]),f2bfbits(r[1]),f2bfbits(r[2]),f2bfbits(r[3]));
            *(ushort4*)(outB + base1) = make_ushort4(f2bfbits(r[4]),f2bfbits(r[5]),f2bfbits(r[6]),f2bfbits(r[7]));
        }
    }
}

// ---------- scores: packed P[s,t] = q.k * scale ; batch = blockIdx.z ----------
__global__ __launch_bounds__(256)
void scores_p(const unsigned short* __restrict__ Qb, const unsigned short* __restrict__ Kb,
              unsigned short* __restrict__ Pb, const float scale)
{
    const int s0 = blockIdx.y * 128, t0 = blockIdx.x * 128;
    if (t0 > s0) return;
    const unsigned short* Q  = Qb + (size_t)blockIdx.z * SD;
    const unsigned short* Km = Kb + (size_t)blockIdx.z * SD;
    unsigned short* P        = Pb + (size_t)blockIdx.z * PPB;
    __shared__ float As[16][132];
    __shared__ float Bs[16][132];
    const int tid = threadIdx.x, tx = tid & 15, ty = tid >> 4;
    const int am = tid >> 1, akb = (tid & 1) * 8;
    float acc[8][8] = {};
    for (int k0 = 0; k0 < DD; k0 += 16){
        uint4 uq = *(const uint4*)(Q  + (size_t)(s0+am)*DD + (k0+akb));
        uint4 uk = *(const uint4*)(Km + (size_t)(t0+am)*DD + (k0+akb));
        float fq[8], fk[8]; unpack8(uq, fq); unpack8(uk, fk);
        #pragma unroll
        for (int j = 0; j < 8; ++j){ As[akb+j][am] = fq[j]; Bs[akb+j][am] = fk[j]; }
        __syncthreads();
        #pragma unroll
        for (int kk = 0; kk < 16; ++kk){
            float a[8], b[8];
            *(float4*)&a[0] = *(const float4*)&As[kk][ty*8];
            *(float4*)&a[4] = *(const float4*)&As[kk][ty*8+4];
            *(float4*)&b[0] = *(const float4*)&Bs[kk][tx*4];
            *(float4*)&b[4] = *(const float4*)&Bs[kk][64+tx*4];
            #pragma unroll
            for (int i = 0; i < 8; ++i)
                #pragma unroll
                for (int j = 0; j < 8; ++j)
                    acc[i][j] = fmaf(a[i], b[j], acc[i][j]);
        }
        __syncthreads();
    }
    #pragma unroll
    for (int i = 0; i < 8; ++i){
        const int s = s0 + ty*8 + i;
        const int width = rowWidth(s);
        unsigned short* pr = P + rowOff(s);
        // group A cols t0+tx*4+{0..3}: always < t0+64 <= width (t0 <= s0 <= s)
        *(ushort4*)(pr + t0 + tx*4) = make_ushort4(
            f2bfbits(acc[i][0]*scale), f2bfbits(acc[i][1]*scale),
            f2bfbits(acc[i][2]*scale), f2bfbits(acc[i][3]*scale));
        if (t0 + 64 < width){
            *(ushort4*)(pr + t0 + 64 + tx*4) = make_ushort4(
                f2bfbits(acc[i][4]*scale), f2bfbits(acc[i][5]*scale),
                f2bfbits(acc[i][6]*scale), f2bfbits(acc[i][7]*scale));
        }
    }
}

// ---------- causal softmax over packed rows; batch = blockIdx.y ----------
__global__ __launch_bounds__(256)
void softmax_p(unsigned short* __restrict__ Pb)
{
    __shared__ float red[4];
    const int s = blockIdx.x;
    const int width = rowWidth(s);
    unsigned short* r = Pb + (size_t)blockIdx.y * PPB + rowOff(s);
    const int tid = threadIdx.x;
    float vals[8];
    float m = -1e30f;
    #pragma unroll
    for (int i = 0; i < 8; ++i){
        int t = tid + i*256;
        float v = -1e30f;
        if (t <= s) v = __uint_as_float(((unsigned)r[t]) << 16);
        vals[i] = v; m = fmaxf(m, v);
    }
    #pragma unroll
    for (int off = 32; off > 0; off >>= 1) m = fmaxf(m, __shfl_down(m, off, 64));
    if ((tid & 63) == 0) red[tid >> 6] = m;
    __syncthreads();
    const float M4 = fmaxf(fmaxf(red[0],red[1]), fmaxf(red[2],red[3]));
    __syncthreads();
    float ev[8]; float sum = 0.f;
    #pragma unroll
    for (int i = 0; i < 8; ++i){ ev[i] = __expf(vals[i] - M4); sum += ev[i]; }
    #pragma unroll
    for (int off = 32; off > 0; off >>= 1) sum += __shfl_down(sum, off, 64);
    if ((tid & 63) == 0) red[tid >> 6] = sum;
    __syncthreads();
    const float inv = 1.0f / (red[0]+red[1]+red[2]+red[3]);
    #pragma unroll
    for (int i = 0; i < 8; ++i){
        int t = tid + i*256;
        if (t < width) r[t] = f2bfbits(ev[i] * inv);
    }
}

// ---------- ctx = P @ v, packed P, K-loop truncated; batch = blockIdx.z ----------
__global__ __launch_bounds__(256)
void pv_p(const unsigned short* __restrict__ Pb, const unsigned short* __restrict__ Vb,
          unsigned short* __restrict__ Cb)
{
    const int s0 = blockIdx.y * 128, n0 = blockIdx.x * 128;
    const unsigned short* P = Pb + (size_t)blockIdx.z * PPB;
    const unsigned short* V = Vb + (size_t)blockIdx.z * SD;
    unsigned short* C       = Cb + (size_t)blockIdx.z * SD;
    __shared__ float As[16][132];
    __shared__ float Bs[16][132];
    const int tid = threadIdx.x, tx = tid & 15, ty = tid >> 4;
    const int am = tid >> 1, akb = (tid & 1) * 8;     // A staging (P transpose)
    const int bk = tid >> 4, bnb = (tid & 15) * 8;    // B staging (V direct)
    float acc[8][8] = {};
    const int kmax = s0 + 128;
    for (int k0 = 0; k0 < kmax; k0 += 16){
        const int s = s0 + am;
        float fa[8] = {0.f,0.f,0.f,0.f,0.f,0.f,0.f,0.f};
        if (k0 + akb < rowWidth(s)){
            uint4 up = *(const uint4*)(P + rowOff(s) + (k0+akb));
            unpack8(up, fa);
        }
        #pragma unroll
        for (int j = 0; j < 8; ++j) As[akb+j][am] = fa[j];
        {
            uint4 uv = *(const uint4*)(V + (size_t)(k0+bk)*DD + (n0+bnb));
            float fv[8]; unpack8(uv, fv);
            *(float4*)&Bs[bk][bnb]   = make_float4(fv[0],fv[1],fv[2],fv[3]);
            *(float4*)&Bs[bk][bnb+4] = make_float4(fv[4],fv[5],fv[6],fv[7]);
        }
        __syncthreads();
        #pragma unroll
        for (int kk = 0; kk < 16; ++kk){
            float a[8], b[8];
            *(float4*)&a[0] = *(const float4*)&As[kk][ty*8];
            *(float4*)&a[4] = *(const float4*)&As[kk][ty*8+4];
            *(float4*)&b[0] = *(const float4*)&Bs[kk][tx*4];
            *(float4*)&b[4] = *(const float4*)&Bs[kk][64+tx*4];
            #pragma unroll
            for (int i = 0; i < 8; ++i)
                #pragma unroll
                for (int j = 0; j < 8; ++j)
                    acc[i][j] = fmaf(a[i], b[j], acc[i][j]);
        }
        __syncthreads();
    }
    #pragma unroll
    for (int i = 0; i < 8; ++i){
        const size_t base0 = (size_t)(s0 + ty*8 + i)*DD + n0 + tx*4;
        *(ushort4*)(C + base0)      = make_ushort4(f2bfbits(acc[i][0]),f2bfbits(acc[i][1]),f2bfbits(acc[i][2]),f2bfbits(acc[i][3]));
        *(ushort4*)(C + base0 + 64) = make_ushort4(f2bfbits(acc[i][4]),f2bfbits(acc[i][5]),f2bfbits(acc[i][6]),f2bfbits(acc[i][7]));
    }
}

extern "C" void kernel_launch(void* const* d_in, const int* in_sizes, int n_in,
                              void* d_out, int out_size, void* d_ws, size_t ws_size,
                              hipStream_t stream)
{
    (void)in_sizes; (void)n_in; (void)out_size;
    const float* x   = (const float*)d_in[0];
    const float* wq  = (const float*)d_in[1];
    const float* bq  = (const float*)d_in[2];
    const float* wk  = (const float*)d_in[3];
    const float* bk  = (const float*)d_in[4];
    const float* wv  = (const float*)d_in[5];
    const float* bv  = (const float*)d_in[6];
    const float* wo  = (const float*)d_in[7];
    const float* bo  = (const float*)d_in[8];
    const float* w1  = (const float*)d_in[9];
    const float* b1  = (const float*)d_in[10];
    const float* w2  = (const float*)d_in[11];
    const float* b2  = (const float*)d_in[12];
    const float* g1  = (const float*)d_in[13];
    const float* be1 = (const float*)d_in[14];
    const float* g2  = (const float*)d_in[15];
    const float* be2 = (const float*)d_in[16];
    float* outf = (float*)d_out;

    const dim3 blk(256);
    const float scale = 1.0f / sqrtf((float)SS);
    unsigned short* wsb = (unsigned short*)d_ws;

    if (ws_size >= (size_t)REQ_FAST){
        // -------- fast path: batch-merged grids --------
        unsigned short* LN1 = wsb;            // -> ctx
        unsigned short* Qw  = wsb + MD;       // -> mid
        unsigned short* Kw  = wsb + 2*MD;     // \ -> h (fp32, spans K+V)
        unsigned short* Vw  = wsb + 3*MD;     // /
        unsigned short* Pw  = wsb + 4*MD;     // packed P (4*PPB) -> ln2
        float*          Hf  = (float*)Kw;
        unsigned short* CTX = LN1;
        unsigned short* LN2 = Pw;
        unsigned short* MIDw= Qw;
        const dim3 g_gemm(DD/128, MM/128);            // (8,64)
        ln_f32<<<dim3(MM), blk, 0, stream>>>(x, g1, be1, LN1);
        gemm_ws<false,false,false><<<g_gemm, blk, 0, stream>>>(LN1, wq, bq, nullptr, Qw, nullptr, MM, DD, DD);
        gemm_ws<false,false,false><<<g_gemm, blk, 0, stream>>>(LN1, wk, bk, nullptr, Kw, nullptr, MM, DD, DD);
        gemm_ws<false,false,false><<<g_gemm, blk, 0, stream>>>(LN1, wv, bv, nullptr, Vw, nullptr, MM, DD, DD);
        scores_p<<<dim3(SS/128, SS/128, BB), blk, 0, stream>>>(Qw, Kw, Pw, scale);
        softmax_p<<<dim3(SS, BB), blk, 0, stream>>>(Pw);
        pv_p<<<dim3(DD/128, SS/128, BB), blk, 0, stream>>>(Pw, Vw, CTX);
        gemm_ws<false,true,true><<<g_gemm, blk, 0, stream>>>(CTX, wo, bo, x, nullptr, Hf, MM, DD, DD);
        ln_f32<<<dim3(MM), blk, 0, stream>>>(Hf, g2, be2, LN2);
        gemm_ws<true,false,false><<<g_gemm, blk, 0, stream>>>(LN2, w1, b1, nullptr, MIDw, nullptr, MM, DD, DD);
        gemm_ws<false,true,true><<<g_gemm, blk, 0, stream>>>(MIDw, w2, b2, Hf, nullptr, outf, MM, DD, DD);
        return;
    }

    if (ws_size < (size_t)REQ_SLOW){
        sentinel_kernel<<<dim3((unsigned)(MD/256)), blk, 0, stream>>>(outf, 1.0e9f);
        return;
    }
    // -------- slow path (proven R4 schedule): per-batch, 16.9 MB --------
    unsigned short* Pp  = wsb;                // packed P; ln1 shares base
    unsigned short* LN1 = wsb;
    unsigned short* Rq  = wsb + PPB;          // q -> ctx -> mid
    unsigned short* Rk  = Rq + SD;            // k; h(f32) overlays Rk+Rv
    unsigned short* Rv  = Rk + SD;            // v
    float*          Hf  = (float*)Rk;
    const dim3 g_gemm(DD/128, SS/128);        // (8,16)
    for (int b = 0; b < BB; ++b){
        const size_t boff = (size_t)b * SD;
        ln_f32<<<dim3(SS), blk, 0, stream>>>(x + boff, g1, be1, LN1);
        gemm_ws<false,false,false><<<g_gemm, blk, 0, stream>>>(LN1, wq, bq, nullptr, Rq, nullptr, SS, DD, DD);
        gemm_ws<false,false,false><<<g_gemm, blk, 0, stream>>>(LN1, wk, bk, nullptr, Rk, nullptr, SS, DD, DD);
        gemm_ws<false,false,false><<<g_gemm, blk, 0, stream>>>(LN1, wv, bv, nullptr, Rv, nullptr, SS, DD, DD);
        scores_p<<<dim3(SS/128, SS/128, 1), blk, 0, stream>>>(Rq, Rk, Pp, scale);
        softmax_p<<<dim3(SS, 1), blk, 0, stream>>>(Pp);
        pv_p<<<dim3(DD/128, SS/128, 1), blk, 0, stream>>>(Pp, Rv, Rq);
        gemm_ws<false,true,true><<<g_gemm, blk, 0, stream>>>(Rq, wo, bo, x + boff, nullptr, Hf, SS, DD, DD);
        ln_f32<<<dim3(SS), blk, 0, stream>>>(Hf, g2, be2, LN1);
        gemm_ws<true,false,false><<<g_gemm, blk, 0, stream>>>(LN1, w1, b1, nullptr, Rq, nullptr, SS, DD, DD);
        gemm_ws<false,true,true><<<g_gemm, blk, 0, stream>>>(Rq, w2, b2, Hf, nullptr, outf + boff, SS, DD, DD);
    }
}

// Round 6
// 906.458 us; speedup vs baseline: 5.9514x; 2.3225x over previous
//
#include <hip/hip_runtime.h>
#include <math.h>

#define BB 4
#define SS 2048
#define DD 1024
#define MM (BB*SS)                   // 8192
#define SD ((size_t)SS*DD)
#define MD ((size_t)MM*DD)           // 8,388,608
#define PPB ((size_t)2162688)        // packed P elems per batch

// ws (bf16 elems): Q@0 | K@MD | VT@2MD | P@3MD (4*PPB) | WT@3MD+4PPB (6*DD*DD)
// Hf (fp32, MD floats) overlays K+VT after both dead; ctx->Q region; mid->P region.
#define WT_OFF (3*MD + 4*PPB)
#define REQ_WS ((WT_OFF + 6*(size_t)DD*DD) * 2)

constexpr float LN_EPS = 1e-6f;

typedef __attribute__((ext_vector_type(8))) __bf16 bf16x8;
typedef __attribute__((ext_vector_type(4))) float f32x4;

__device__ __forceinline__ unsigned short f2bfbits(float f){
    unsigned u = __float_as_uint(f);
    u += 0x7FFFu + ((u >> 16) & 1u);   // RNE
    return (unsigned short)(u >> 16);
}
// packed causal rows: row s keeps cols [0, 64*(g+1)), g = s>>6
__device__ __forceinline__ int rowWidth(int s){ return ((s >> 6) + 1) << 6; }
__device__ __forceinline__ size_t rowOff(int s){
    int g = s >> 6;
    return (size_t)4096 * (size_t)((g * (g + 1)) >> 1) + (size_t)(s & 63) * (size_t)((g + 1) << 6);
}

__global__ __launch_bounds__(256)
void sentinel_kernel(float* __restrict__ out, const float val){
    out[(size_t)blockIdx.x * 256 + threadIdx.x] = val;
}

// ---------- weight transpose + bf16 convert: W[K][N] f32 -> WT[N][K] bf16 ----------
struct WPack { const float* w[6]; unsigned short* o[6]; };
__global__ __launch_bounds__(256)
void wtrans(WPack wp)
{
    __shared__ float Ts[64][65];
    const float* W = wp.w[blockIdx.z];
    unsigned short* WT = wp.o[blockIdx.z];
    const int r0 = blockIdx.y*64, c0 = blockIdx.x*64;
    const int tid = threadIdx.x;
    #pragma unroll
    for (int i = 0; i < 16; ++i){
        int lin = tid + i*256;
        int r = lin >> 6, c = lin & 63;
        Ts[r][c] = W[(size_t)(r0+r)*DD + c0+c];
    }
    __syncthreads();
    #pragma unroll
    for (int i = 0; i < 16; ++i){
        int lin = tid + i*256;
        int r = lin >> 6, c = lin & 63;
        WT[(size_t)(c0+r)*DD + r0+c] = f2bfbits(Ts[c][r]);
    }
}

// ---------- LayerNorm: fp32 in -> bf16 out. ddof=1 std, eps on std ----------
__global__ __launch_bounds__(256)
void ln_f32(const float* __restrict__ x, const float* __restrict__ gamma,
            const float* __restrict__ beta, unsigned short* __restrict__ out)
{
    __shared__ float red[4];
    const int row = blockIdx.x;
    const int tid = threadIdx.x;
    float4 xv = ((const float4*)(x + (size_t)row*DD))[tid];
    float v[4] = {xv.x, xv.y, xv.z, xv.w};
    float s = v[0]+v[1]+v[2]+v[3];
    #pragma unroll
    for (int off = 32; off > 0; off >>= 1) s += __shfl_down(s, off, 64);
    if ((tid & 63) == 0) red[tid >> 6] = s;
    __syncthreads();
    const float mean = (red[0]+red[1]+red[2]+red[3]) * (1.0f/DD);
    __syncthreads();
    float q = 0.f;
    #pragma unroll
    for (int i = 0; i < 4; ++i){ float d = v[i]-mean; q += d*d; }
    #pragma unroll
    for (int off = 32; off > 0; off >>= 1) q += __shfl_down(q, off, 64);
    if ((tid & 63) == 0) red[tid >> 6] = q;
    __syncthreads();
    const float var = (red[0]+red[1]+red[2]+red[3]) * (1.0f/(DD-1));
    const float inv = 1.0f/(sqrtf(var) + LN_EPS);
    float4 g4 = ((const float4*)gamma)[tid];
    float4 b4 = ((const float4*)beta)[tid];
    ushort4 o;
    o.x = f2bfbits(g4.x*(v[0]-mean)*inv + b4.x);
    o.y = f2bfbits(g4.y*(v[1]-mean)*inv + b4.y);
    o.z = f2bfbits(g4.z*(v[2]-mean)*inv + b4.z);
    o.w = f2bfbits(g4.w*(v[3]-mean)*inv + b4.w);
    ((ushort4*)(out + (size_t)row*DD))[tid] = o;
}

// ---------- MFMA GEMM: C[M,N] = Aop[M,K] * Bop[N,K]^T (+bias)(relu)(+res) ----------
// 128x128 tile, BK=64, 4 waves in 2x2, each 64x64 (4x4 of 16x16x32 mfma).
// LDS rows padded to 72 bf16 (fragment reads 2-way max).
template<bool RELU, bool RES, bool OUTF, bool BIAS_M>
__global__ __launch_bounds__(256)
void gemm_mfma(const unsigned short* __restrict__ A, const unsigned short* __restrict__ B,
               const float* __restrict__ bias, const float* __restrict__ resF,
               unsigned short* __restrict__ outB, float* __restrict__ outF,
               const int M, const int N, const int K, const int lda, const int ldb)
{
    __shared__ unsigned short As[128*72];
    __shared__ unsigned short Bs[128*72];
    const int m0 = blockIdx.y*128, n0 = blockIdx.x*128;
    const int tid = threadIdx.x;
    const int lane = tid & 63;
    const int wm = ((tid >> 7) & 1) * 64;      // wave row (waves 2,3 -> lower half)
    const int wn = ((tid >> 6) & 1) * 64;      // wave col
    const int quad = lane >> 4, l15 = lane & 15;
    const int prow = tid >> 3, pg = tid & 7;   // staging: row 0..31 (+p*32), granule 0..7
    f32x4 acc[4][4] = {};
    for (int k0 = 0; k0 < K; k0 += 64){
        uint4 la[4], lb[4];
        #pragma unroll
        for (int p = 0; p < 4; ++p){
            la[p] = *(const uint4*)(A + (size_t)(m0 + p*32 + prow)*lda + k0 + pg*8);
            lb[p] = *(const uint4*)(B + (size_t)(n0 + p*32 + prow)*ldb + k0 + pg*8);
        }
        __syncthreads();
        #pragma unroll
        for (int p = 0; p < 4; ++p){
            *(uint4*)&As[(p*32 + prow)*72 + pg*8] = la[p];
            *(uint4*)&Bs[(p*32 + prow)*72 + pg*8] = lb[p];
        }
        __syncthreads();
        #pragma unroll
        for (int kk = 0; kk < 2; ++kk){
            bf16x8 af[4], bfr[4];
            #pragma unroll
            for (int t = 0; t < 4; ++t){
                af[t]  = *(const bf16x8*)&As[(wm + t*16 + l15)*72 + kk*32 + quad*8];
                bfr[t] = *(const bf16x8*)&Bs[(wn + t*16 + l15)*72 + kk*32 + quad*8];
            }
            #pragma unroll
            for (int i = 0; i < 4; ++i)
                #pragma unroll
                for (int j = 0; j < 4; ++j)
                    acc[i][j] = __builtin_amdgcn_mfma_f32_16x16x32_bf16(af[i], bfr[j], acc[i][j], 0, 0, 0);
        }
    }
    #pragma unroll
    for (int i = 0; i < 4; ++i){
        #pragma unroll
        for (int r = 0; r < 4; ++r){
            const int m = m0 + wm + i*16 + quad*4 + r;
            const float bm = BIAS_M ? bias[m] : 0.f;
            #pragma unroll
            for (int j = 0; j < 4; ++j){
                const int n = n0 + wn + j*16 + l15;
                float v = acc[i][j][r] + (BIAS_M ? bm : bias[n]);
                if constexpr (RELU) v = fmaxf(v, 0.f);
                if constexpr (RES) v += resF[(size_t)m*N + n];
                if constexpr (OUTF) outF[(size_t)m*N + n] = v;
                else outB[(size_t)m*N + n] = f2bfbits(v);
            }
        }
    }
}

// ---------- scores: packed P = Q*K^T * scale (causal block-skip) ----------
__global__ __launch_bounds__(256)
void scores_mfma(const unsigned short* __restrict__ Qb, const unsigned short* __restrict__ Kb,
                 unsigned short* __restrict__ Pb, const float scale)
{
    const int s0 = blockIdx.y*128, t0 = blockIdx.x*128;
    if (t0 > s0) return;
    const unsigned short* Q  = Qb + (size_t)blockIdx.z*SD;
    const unsigned short* Km = Kb + (size_t)blockIdx.z*SD;
    unsigned short* P        = Pb + (size_t)blockIdx.z*PPB;
    __shared__ unsigned short As[128*72];
    __shared__ unsigned short Bs[128*72];
    const int tid = threadIdx.x;
    const int lane = tid & 63;
    const int wm = ((tid >> 7) & 1) * 64, wn = ((tid >> 6) & 1) * 64;
    const int quad = lane >> 4, l15 = lane & 15;
    const int prow = tid >> 3, pg = tid & 7;
    f32x4 acc[4][4] = {};
    for (int k0 = 0; k0 < DD; k0 += 64){
        uint4 la[4], lb[4];
        #pragma unroll
        for (int p = 0; p < 4; ++p){
            la[p] = *(const uint4*)(Q  + (size_t)(s0 + p*32 + prow)*DD + k0 + pg*8);
            lb[p] = *(const uint4*)(Km + (size_t)(t0 + p*32 + prow)*DD + k0 + pg*8);
        }
        __syncthreads();
        #pragma unroll
        for (int p = 0; p < 4; ++p){
            *(uint4*)&As[(p*32 + prow)*72 + pg*8] = la[p];
            *(uint4*)&Bs[(p*32 + prow)*72 + pg*8] = lb[p];
        }
        __syncthreads();
        #pragma unroll
        for (int kk = 0; kk < 2; ++kk){
            bf16x8 af[4], bfr[4];
            #pragma unroll
            for (int t = 0; t < 4; ++t){
                af[t]  = *(const bf16x8*)&As[(wm + t*16 + l15)*72 + kk*32 + quad*8];
                bfr[t] = *(const bf16x8*)&Bs[(wn + t*16 + l15)*72 + kk*32 + quad*8];
            }
            #pragma unroll
            for (int i = 0; i < 4; ++i)
                #pragma unroll
                for (int j = 0; j < 4; ++j)
                    acc[i][j] = __builtin_amdgcn_mfma_f32_16x16x32_bf16(af[i], bfr[j], acc[i][j], 0, 0, 0);
        }
    }
    #pragma unroll
    for (int i = 0; i < 4; ++i){
        #pragma unroll
        for (int r = 0; r < 4; ++r){
            const int s = s0 + wm + i*16 + quad*4 + r;
            const int width = rowWidth(s);
            unsigned short* pr = P + rowOff(s);
            #pragma unroll
            for (int j = 0; j < 4; ++j){
                const int t = t0 + wn + j*16 + l15;
                if (t < width) pr[t] = f2bfbits(acc[i][j][r] * scale);
            }
        }
    }
}

// ---------- causal softmax over packed rows ----------
__global__ __launch_bounds__(256)
void softmax_p(unsigned short* __restrict__ Pb)
{
    __shared__ float red[4];
    const int s = blockIdx.x;
    const int width = rowWidth(s);
    unsigned short* r = Pb + (size_t)blockIdx.y * PPB + rowOff(s);
    const int tid = threadIdx.x;
    float vals[8];
    float m = -1e30f;
    #pragma unroll
    for (int i = 0; i < 8; ++i){
        int t = tid + i*256;
        float v = -1e30f;
        if (t <= s) v = __uint_as_float(((unsigned)r[t]) << 16);
        vals[i] = v; m = fmaxf(m, v);
    }
    #pragma unroll
    for (int off = 32; off > 0; off >>= 1) m = fmaxf(m, __shfl_down(m, off, 64));
    if ((tid & 63) == 0) red[tid >> 6] = m;
    __syncthreads();
    const float M4 = fmaxf(fmaxf(red[0],red[1]), fmaxf(red[2],red[3]));
    __syncthreads();
    float ev[8]; float sum = 0.f;
    #pragma unroll
    for (int i = 0; i < 8; ++i){ ev[i] = __expf(vals[i] - M4); sum += ev[i]; }
    #pragma unroll
    for (int off = 32; off > 0; off >>= 1) sum += __shfl_down(sum, off, 64);
    if ((tid & 63) == 0) red[tid >> 6] = sum;
    __syncthreads();
    const float inv = 1.0f / (red[0]+red[1]+red[2]+red[3]);
    #pragma unroll
    for (int i = 0; i < 8; ++i){
        int t = tid + i*256;
        if (t < width) r[t] = f2bfbits(ev[i] * inv);
    }
}

// ---------- ctx = P @ V, A=packed P[s][t], B=VT[d][tok] (t-contig), K truncated ----------
__global__ __launch_bounds__(256)
void pv_mfma(const unsigned short* __restrict__ Pb, const unsigned short* __restrict__ VT,
             unsigned short* __restrict__ Cb)
{
    const int s0 = blockIdx.y*128, n0 = blockIdx.x*128;   // n = d
    const unsigned short* P = Pb + (size_t)blockIdx.z*PPB;
    unsigned short* C       = Cb + (size_t)blockIdx.z*SD;
    const int bcol = blockIdx.z*SS;
    __shared__ unsigned short As[128*72];
    __shared__ unsigned short Bs[128*72];
    const int tid = threadIdx.x;
    const int lane = tid & 63;
    const int wm = ((tid >> 7) & 1) * 64, wn = ((tid >> 6) & 1) * 64;
    const int quad = lane >> 4, l15 = lane & 15;
    const int prow = tid >> 3, pg = tid & 7;
    f32x4 acc[4][4] = {};
    const int kmax = s0 + 128;
    for (int k0 = 0; k0 < kmax; k0 += 64){
        uint4 la[4], lb[4];
        #pragma unroll
        for (int p = 0; p < 4; ++p){
            const int s = s0 + p*32 + prow;
            la[p] = (k0 < rowWidth(s)) ? *(const uint4*)(P + rowOff(s) + k0 + pg*8)
                                       : make_uint4(0u,0u,0u,0u);
            lb[p] = *(const uint4*)(VT + (size_t)(n0 + p*32 + prow)*MM + bcol + k0 + pg*8);
        }
        __syncthreads();
        #pragma unroll
        for (int p = 0; p < 4; ++p){
            *(uint4*)&As[(p*32 + prow)*72 + pg*8] = la[p];
            *(uint4*)&Bs[(p*32 + prow)*72 + pg*8] = lb[p];
        }
        __syncthreads();
        #pragma unroll
        for (int kk = 0; kk < 2; ++kk){
            bf16x8 af[4], bfr[4];
            #pragma unroll
            for (int t = 0; t < 4; ++t){
                af[t]  = *(const bf16x8*)&As[(wm + t*16 + l15)*72 + kk*32 + quad*8];
                bfr[t] = *(const bf16x8*)&Bs[(wn + t*16 + l15)*72 + kk*32 + quad*8];
            }
            #pragma unroll
            for (int i = 0; i < 4; ++i)
                #pragma unroll
                for (int j = 0; j < 4; ++j)
                    acc[i][j] = __builtin_amdgcn_mfma_f32_16x16x32_bf16(af[i], bfr[j], acc[i][j], 0, 0, 0);
        }
    }
    #pragma unroll
    for (int i = 0; i < 4; ++i){
        #pragma unroll
        for (int r = 0; r < 4; ++r){
            const int s = s0 + wm + i*16 + quad*4 + r;
            #pragma unroll
            for (int j = 0; j < 4; ++j){
                const int n = n0 + wn + j*16 + l15;
                C[(size_t)s*DD + n] = f2bfbits(acc[i][j][r]);
            }
        }
    }
}

extern "C" void kernel_launch(void* const* d_in, const int* in_sizes, int n_in,
                              void* d_out, int out_size, void* d_ws, size_t ws_size,
                              hipStream_t stream)
{
    (void)in_sizes; (void)n_in; (void)out_size;
    const float* x   = (const float*)d_in[0];
    const float* bq  = (const float*)d_in[2];
    const float* bk  = (const float*)d_in[4];
    const float* bv  = (const float*)d_in[6];
    const float* bo  = (const float*)d_in[8];
    const float* b1  = (const float*)d_in[10];
    const float* b2  = (const float*)d_in[12];
    const float* g1  = (const float*)d_in[13];
    const float* be1 = (const float*)d_in[14];
    const float* g2  = (const float*)d_in[15];
    const float* be2 = (const float*)d_in[16];
    float* outf = (float*)d_out;

    if (ws_size < (size_t)REQ_WS){
        sentinel_kernel<<<dim3((unsigned)(MD/256)), dim3(256), 0, stream>>>(outf, 1.0e9f);
        return;
    }

    unsigned short* wsb = (unsigned short*)d_ws;
    unsigned short* Qw  = wsb;                 // -> ctx
    unsigned short* Kw  = wsb + MD;            // \ -> Hf (fp32 spans K+VT)
    unsigned short* VTw = wsb + 2*MD;          // /
    unsigned short* Pw  = wsb + 3*MD;          // packed P -> mid
    unsigned short* WT  = wsb + WT_OFF;        // 6 transposed bf16 weights
    float*          Hf  = (float*)Kw;
    unsigned short* CTX = Qw;
    unsigned short* MIDw= Pw;
    unsigned short* LN  = (unsigned short*)d_out;   // LN1 then LN2 (d_out scratch)

    WPack wp;
    for (int i = 0; i < 6; ++i){
        static const int widx[6] = {1,3,5,7,9,11};
        wp.w[i] = (const float*)d_in[widx[i]];
        wp.o[i] = WT + (size_t)i*DD*DD;
    }
    unsigned short* WqT = wp.o[0]; unsigned short* WkT = wp.o[1];
    unsigned short* WvT = wp.o[2]; unsigned short* WoT = wp.o[3];
    unsigned short* W1T = wp.o[4]; unsigned short* W2T = wp.o[5];

    const dim3 blk(256);
    const float scale = 1.0f / sqrtf((float)SS);
    const dim3 gA(DD/128, MM/128);    // (8,64): [8192 x 1024] outputs
    const dim3 gVT(MM/128, DD/128);   // (64,8): VT [1024 x 8192]

    wtrans<<<dim3(16,16,6), blk, 0, stream>>>(wp);
    ln_f32<<<dim3(MM), blk, 0, stream>>>(x, g1, be1, LN);
    // Q = LN*WqT^T ; K = LN*WkT^T
    gemm_mfma<false,false,false,false><<<gA, blk, 0, stream>>>(LN, WqT, bq, nullptr, Qw, nullptr, MM, DD, DD, DD, DD);
    gemm_mfma<false,false,false,false><<<gA, blk, 0, stream>>>(LN, WkT, bk, nullptr, Kw, nullptr, MM, DD, DD, DD, DD);
    // VT[d][tok] = WvT[d][k] . LN[tok][k]  (bias along m=d)
    gemm_mfma<false,false,false,true ><<<gVT, blk, 0, stream>>>(WvT, LN, bv, nullptr, VTw, nullptr, DD, MM, DD, DD, DD);
    // attention
    scores_mfma<<<dim3(SS/128, SS/128, BB), blk, 0, stream>>>(Qw, Kw, Pw, scale);
    softmax_p<<<dim3(SS, BB), blk, 0, stream>>>(Pw);
    pv_mfma<<<dim3(DD/128, SS/128, BB), blk, 0, stream>>>(Pw, VTw, CTX);
    // h = ctx*WoT^T + bo + x  (fp32, overlays K+VT)
    gemm_mfma<false,true,true,false><<<gA, blk, 0, stream>>>(CTX, WoT, bo, x, nullptr, Hf, MM, DD, DD, DD, DD);
    ln_f32<<<dim3(MM), blk, 0, stream>>>(Hf, g2, be2, LN);
    // mid = relu(LN*W1T^T + b1)
    gemm_mfma<true,false,false,false><<<gA, blk, 0, stream>>>(LN, W1T, b1, nullptr, MIDw, nullptr, MM, DD, DD, DD, DD);
    // out = mid*W2T^T + b2 + h
    gemm_mfma<false,true,true,false><<<gA, blk, 0, stream>>>(MIDw, W2T, b2, Hf, nullptr, outf, MM, DD, DD, DD, DD);
}

// Round 7
// 396.962 us; speedup vs baseline: 13.5900x; 2.2835x over previous
//
#include <hip/hip_runtime.h>
#include <math.h>

#define BB 4
#define SS 2048
#define DD 1024
#define MM (BB*SS)                   // 8192
#define SD ((size_t)SS*DD)
#define MD ((size_t)MM*DD)           // 8,388,608
#define PPB ((size_t)2162688)        // packed P elems per batch

// ws (bf16 elems): Q@0 | K@MD | VT@2MD | P@3MD (4*PPB) | WT@3MD+4PPB (6*DD*DD) | zpad(16)
#define WT_OFF (3*MD + 4*PPB)
#define ZP_OFF (WT_OFF + 6*(size_t)DD*DD)
#define REQ_WS ((ZP_OFF + 16) * 2)

constexpr float LN_EPS = 1e-6f;

typedef __attribute__((ext_vector_type(8))) __bf16 bf16x8;
typedef __attribute__((ext_vector_type(4))) float f32x4;

__device__ __forceinline__ unsigned short f2bfbits(float f){
    unsigned u = __float_as_uint(f);
    u += 0x7FFFu + ((u >> 16) & 1u);   // RNE
    return (unsigned short)(u >> 16);
}
__device__ __forceinline__ int rowWidth(int s){ return ((s >> 6) + 1) << 6; }
__device__ __forceinline__ size_t rowOff(int s){
    int g = s >> 6;
    return (size_t)4096 * (size_t)((g * (g + 1)) >> 1) + (size_t)(s & 63) * (size_t)((g + 1) << 6);
}
// async global->LDS, 16B per lane; LDS dest = wave-uniform base + lane*16
__device__ __forceinline__ void gl_lds(const unsigned short* g, unsigned short* l){
    __builtin_amdgcn_global_load_lds(
        (const __attribute__((address_space(1))) unsigned int*)g,
        (__attribute__((address_space(3))) unsigned int*)l, 16, 0, 0);
}

__global__ __launch_bounds__(256)
void sentinel_kernel(float* __restrict__ out, const float val){
    out[(size_t)blockIdx.x * 256 + threadIdx.x] = val;
}

// ---------- weight transpose W[K][N] f32 -> WT[N][K] bf16 ; also zeroes zpad ----------
struct WPack { const float* w[6]; unsigned short* o[6]; unsigned short* zp; };
__global__ __launch_bounds__(256)
void wtrans(WPack wp)
{
    __shared__ float Ts[64][65];
    const float* W = wp.w[blockIdx.z];
    unsigned short* WT = wp.o[blockIdx.z];
    const int r0 = blockIdx.y*64, c0 = blockIdx.x*64;
    const int tid = threadIdx.x;
    if (blockIdx.x == 0 && blockIdx.y == 0 && blockIdx.z == 0 && tid < 16) wp.zp[tid] = 0;
    #pragma unroll
    for (int i = 0; i < 16; ++i){
        int lin = tid + i*256;
        int r = lin >> 6, c = lin & 63;
        Ts[r][c] = W[(size_t)(r0+r)*DD + c0+c];
    }
    __syncthreads();
    #pragma unroll
    for (int i = 0; i < 16; ++i){
        int lin = tid + i*256;
        int r = lin >> 6, c = lin & 63;
        WT[(size_t)(c0+r)*DD + r0+c] = f2bfbits(Ts[c][r]);
    }
}

// ---------- LayerNorm: fp32 in -> bf16 out ----------
__global__ __launch_bounds__(256)
void ln_f32(const float* __restrict__ x, const float* __restrict__ gamma,
            const float* __restrict__ beta, unsigned short* __restrict__ out)
{
    __shared__ float red[4];
    const int row = blockIdx.x;
    const int tid = threadIdx.x;
    float4 xv = ((const float4*)(x + (size_t)row*DD))[tid];
    float v[4] = {xv.x, xv.y, xv.z, xv.w};
    float s = v[0]+v[1]+v[2]+v[3];
    #pragma unroll
    for (int off = 32; off > 0; off >>= 1) s += __shfl_down(s, off, 64);
    if ((tid & 63) == 0) red[tid >> 6] = s;
    __syncthreads();
    const float mean = (red[0]+red[1]+red[2]+red[3]) * (1.0f/DD);
    __syncthreads();
    float q = 0.f;
    #pragma unroll
    for (int i = 0; i < 4; ++i){ float d = v[i]-mean; q += d*d; }
    #pragma unroll
    for (int off = 32; off > 0; off >>= 1) q += __shfl_down(q, off, 64);
    if ((tid & 63) == 0) red[tid >> 6] = q;
    __syncthreads();
    const float var = (red[0]+red[1]+red[2]+red[3]) * (1.0f/(DD-1));
    const float inv = 1.0f/(sqrtf(var) + LN_EPS);
    float4 g4 = ((const float4*)gamma)[tid];
    float4 b4 = ((const float4*)beta)[tid];
    ushort4 o;
    o.x = f2bfbits(g4.x*(v[0]-mean)*inv + b4.x);
    o.y = f2bfbits(g4.y*(v[1]-mean)*inv + b4.y);
    o.z = f2bfbits(g4.z*(v[2]-mean)*inv + b4.z);
    o.w = f2bfbits(g4.w*(v[3]-mean)*inv + b4.w);
    ((ushort4*)(out + (size_t)row*DD))[tid] = o;
}

// =========== MFMA GEMM core: C[128,128] tile of A[M,K]*B[N,K]^T ===========
// BK=64, 4 waves 2x2, each 64x64. global_load_lds staging, granule-rotated LDS.
// LDS tile: row m (64 shorts), granule g stored at slot (g+m)&7.
template<bool RELU, bool RES, bool OUTF, bool BIAS_M>
__device__ __forceinline__ void gemm_core(
    const unsigned short* __restrict__ A, const unsigned short* __restrict__ B,
    const float* __restrict__ bias, const float* __restrict__ resF,
    unsigned short* __restrict__ outB, float* __restrict__ outF,
    const int N, const int K, const int lda, const int ldb,
    const int m0, const int n0,
    unsigned short* As, unsigned short* Bs)
{
    const int tid = threadIdx.x, lane = tid & 63, wave = tid >> 6;
    const int wm = ((wave >> 1) & 1) * 64, wn = (wave & 1) * 64;
    const int quad = lane >> 4, l15 = lane & 15;
    const unsigned short* ga[4]; const unsigned short* gb[4];
    #pragma unroll
    for (int c = 0; c < 4; ++c){
        const int mr = (wave*4 + c)*8 + (lane >> 3);
        const int gk = ((lane & 7) - mr) & 7;
        ga[c] = A + (size_t)(m0 + mr)*lda + gk*8;
        gb[c] = B + (size_t)(n0 + mr)*ldb + gk*8;
    }
    f32x4 acc[4][4] = {};
    for (int k0 = 0; k0 < K; k0 += 64){
        #pragma unroll
        for (int c = 0; c < 4; ++c){
            gl_lds(ga[c] + k0, &As[(wave*4+c)*512]);
            gl_lds(gb[c] + k0, &Bs[(wave*4+c)*512]);
        }
        __syncthreads();
        #pragma unroll
        for (int kk = 0; kk < 2; ++kk){
            bf16x8 af[4], bfr[4];
            #pragma unroll
            for (int t = 0; t < 4; ++t){
                const int ra = wm + t*16 + l15, rb = wn + t*16 + l15, gi = kk*4 + quad;
                af[t]  = *(const bf16x8*)&As[ra*64 + (((gi + ra) & 7) << 3)];
                bfr[t] = *(const bf16x8*)&Bs[rb*64 + (((gi + rb) & 7) << 3)];
            }
            #pragma unroll
            for (int i = 0; i < 4; ++i)
                #pragma unroll
                for (int j = 0; j < 4; ++j)
                    acc[i][j] = __builtin_amdgcn_mfma_f32_16x16x32_bf16(af[i], bfr[j], acc[i][j], 0, 0, 0);
        }
        __syncthreads();
    }
    #pragma unroll
    for (int i = 0; i < 4; ++i){
        #pragma unroll
        for (int r = 0; r < 4; ++r){
            const int m = m0 + wm + i*16 + quad*4 + r;
            const float bm = BIAS_M ? bias[m] : 0.f;
            #pragma unroll
            for (int j = 0; j < 4; ++j){
                const int n = n0 + wn + j*16 + l15;
                float v = acc[i][j][r] + (BIAS_M ? bm : bias[n]);
                if constexpr (RELU) v = fmaxf(v, 0.f);
                if constexpr (RES) v += resF[(size_t)m*N + n];
                if constexpr (OUTF) outF[(size_t)m*N + n] = v;
                else outB[(size_t)m*N + n] = f2bfbits(v);
            }
        }
    }
}

// generic single GEMM
template<bool RELU, bool RES, bool OUTF, bool BIAS_M>
__global__ __launch_bounds__(256)
void gemm_mfma(const unsigned short* __restrict__ A, const unsigned short* __restrict__ B,
               const float* __restrict__ bias, const float* __restrict__ resF,
               unsigned short* __restrict__ outB, float* __restrict__ outF,
               const int N, const int K, const int lda, const int ldb)
{
    __shared__ unsigned short As[128*64];
    __shared__ unsigned short Bs[128*64];
    gemm_core<RELU,RES,OUTF,BIAS_M>(A, B, bias, resF, outB, outF, N, K, lda, ldb,
                                    blockIdx.y*128, blockIdx.x*128, As, Bs);
}

// merged Q+K projection (z=0 -> Q, z=1 -> K)
__global__ __launch_bounds__(256)
void gemm_qk(const unsigned short* __restrict__ LN,
             const unsigned short* __restrict__ WqT, const unsigned short* __restrict__ WkT,
             const float* __restrict__ bq, const float* __restrict__ bk,
             unsigned short* __restrict__ Qw, unsigned short* __restrict__ Kw)
{
    __shared__ unsigned short As[128*64];
    __shared__ unsigned short Bs[128*64];
    const bool isK = (blockIdx.z != 0);
    gemm_core<false,false,false,false>(LN, isK ? WkT : WqT, isK ? bk : bq, nullptr,
                                       isK ? Kw : Qw, nullptr, DD, DD, DD, DD,
                                       blockIdx.y*128, blockIdx.x*128, As, Bs);
}

// ---------- scores: packed P = Q*K^T * scale (causal block-skip) ----------
__global__ __launch_bounds__(256)
void scores_mfma(const unsigned short* __restrict__ Qb, const unsigned short* __restrict__ Kb,
                 unsigned short* __restrict__ Pb, const float scale)
{
    const int s0 = blockIdx.y*128, t0 = blockIdx.x*128;
    if (t0 > s0) return;
    const unsigned short* Q  = Qb + (size_t)blockIdx.z*SD;
    const unsigned short* Km = Kb + (size_t)blockIdx.z*SD;
    unsigned short* P        = Pb + (size_t)blockIdx.z*PPB;
    __shared__ unsigned short As[128*64];
    __shared__ unsigned short Bs[128*64];
    const int tid = threadIdx.x, lane = tid & 63, wave = tid >> 6;
    const int wm = ((wave >> 1) & 1) * 64, wn = (wave & 1) * 64;
    const int quad = lane >> 4, l15 = lane & 15;
    const unsigned short* ga[4]; const unsigned short* gb[4];
    #pragma unroll
    for (int c = 0; c < 4; ++c){
        const int mr = (wave*4 + c)*8 + (lane >> 3);
        const int gk = ((lane & 7) - mr) & 7;
        ga[c] = Q  + (size_t)(s0 + mr)*DD + gk*8;
        gb[c] = Km + (size_t)(t0 + mr)*DD + gk*8;
    }
    f32x4 acc[4][4] = {};
    for (int k0 = 0; k0 < DD; k0 += 64){
        #pragma unroll
        for (int c = 0; c < 4; ++c){
            gl_lds(ga[c] + k0, &As[(wave*4+c)*512]);
            gl_lds(gb[c] + k0, &Bs[(wave*4+c)*512]);
        }
        __syncthreads();
        #pragma unroll
        for (int kk = 0; kk < 2; ++kk){
            bf16x8 af[4], bfr[4];
            #pragma unroll
            for (int t = 0; t < 4; ++t){
                const int ra = wm + t*16 + l15, rb = wn + t*16 + l15, gi = kk*4 + quad;
                af[t]  = *(const bf16x8*)&As[ra*64 + (((gi + ra) & 7) << 3)];
                bfr[t] = *(const bf16x8*)&Bs[rb*64 + (((gi + rb) & 7) << 3)];
            }
            #pragma unroll
            for (int i = 0; i < 4; ++i)
                #pragma unroll
                for (int j = 0; j < 4; ++j)
                    acc[i][j] = __builtin_amdgcn_mfma_f32_16x16x32_bf16(af[i], bfr[j], acc[i][j], 0, 0, 0);
        }
        __syncthreads();
    }
    #pragma unroll
    for (int i = 0; i < 4; ++i){
        #pragma unroll
        for (int r = 0; r < 4; ++r){
            const int s = s0 + wm + i*16 + quad*4 + r;
            const int width = rowWidth(s);
            unsigned short* pr = P + rowOff(s);
            #pragma unroll
            for (int j = 0; j < 4; ++j){
                const int t = t0 + wn + j*16 + l15;
                if (t < width) pr[t] = f2bfbits(acc[i][j][r] * scale);
            }
        }
    }
}

// ---------- causal softmax over packed rows ----------
__global__ __launch_bounds__(256)
void softmax_p(unsigned short* __restrict__ Pb)
{
    __shared__ float red[4];
    const int s = blockIdx.x;
    const int width = rowWidth(s);
    unsigned short* r = Pb + (size_t)blockIdx.y * PPB + rowOff(s);
    const int tid = threadIdx.x;
    float vals[8];
    float m = -1e30f;
    #pragma unroll
    for (int i = 0; i < 8; ++i){
        int t = tid + i*256;
        float v = -1e30f;
        if (t <= s) v = __uint_as_float(((unsigned)r[t]) << 16);
        vals[i] = v; m = fmaxf(m, v);
    }
    #pragma unroll
    for (int off = 32; off > 0; off >>= 1) m = fmaxf(m, __shfl_down(m, off, 64));
    if ((tid & 63) == 0) red[tid >> 6] = m;
    __syncthreads();
    const float M4 = fmaxf(fmaxf(red[0],red[1]), fmaxf(red[2],red[3]));
    __syncthreads();
    float ev[8]; float sum = 0.f;
    #pragma unroll
    for (int i = 0; i < 8; ++i){ ev[i] = __expf(vals[i] - M4); sum += ev[i]; }
    #pragma unroll
    for (int off = 32; off > 0; off >>= 1) sum += __shfl_down(sum, off, 64);
    if ((tid & 63) == 0) red[tid >> 6] = sum;
    __syncthreads();
    const float inv = 1.0f / (red[0]+red[1]+red[2]+red[3]);
    #pragma unroll
    for (int i = 0; i < 8; ++i){
        int t = tid + i*256;
        if (t < width) r[t] = f2bfbits(ev[i] * inv);
    }
}

// ---------- ctx = P @ V ; A=packed P (zpad for masked rows), B=VT[d][tok] ----------
__global__ __launch_bounds__(256)
void pv_mfma(const unsigned short* __restrict__ Pb, const unsigned short* __restrict__ VT,
             unsigned short* __restrict__ Cb, const unsigned short* __restrict__ zpad)
{
    const int s0 = blockIdx.y*128, n0 = blockIdx.x*128;
    const unsigned short* P = Pb + (size_t)blockIdx.z*PPB;
    unsigned short* C       = Cb + (size_t)blockIdx.z*SD;
    const int bcol = blockIdx.z*SS;
    __shared__ unsigned short As[128*64];
    __shared__ unsigned short Bs[128*64];
    const int tid = threadIdx.x, lane = tid & 63, wave = tid >> 6;
    const int wm = ((wave >> 1) & 1) * 64, wn = (wave & 1) * 64;
    const int quad = lane >> 4, l15 = lane & 15;
    const unsigned short* ga[4]; const unsigned short* gb[4]; int pw[4];
    #pragma unroll
    for (int c = 0; c < 4; ++c){
        const int mr = (wave*4 + c)*8 + (lane >> 3);
        const int gk = ((lane & 7) - mr) & 7;
        const int s = s0 + mr;
        pw[c] = rowWidth(s) - gk*8;                 // valid iff k0 < pw (both mult of 64 logic holds)
        ga[c] = P + rowOff(s) + gk*8;
        gb[c] = VT + (size_t)(n0 + mr)*MM + bcol + gk*8;
    }
    f32x4 acc[4][4] = {};
    const int kmax = s0 + 128;
    for (int k0 = 0; k0 < kmax; k0 += 64){
        #pragma unroll
        for (int c = 0; c < 4; ++c){
            const unsigned short* gp = (k0 < pw[c]) ? (ga[c] + k0) : zpad;
            gl_lds(gp, &As[(wave*4+c)*512]);
            gl_lds(gb[c] + k0, &Bs[(wave*4+c)*512]);
        }
        __syncthreads();
        #pragma unroll
        for (int kk = 0; kk < 2; ++kk){
            bf16x8 af[4], bfr[4];
            #pragma unroll
            for (int t = 0; t < 4; ++t){
                const int ra = wm + t*16 + l15, rb = wn + t*16 + l15, gi = kk*4 + quad;
                af[t]  = *(const bf16x8*)&As[ra*64 + (((gi + ra) & 7) << 3)];
                bfr[t] = *(const bf16x8*)&Bs[rb*64 + (((gi + rb) & 7) << 3)];
            }
            #pragma unroll
            for (int i = 0; i < 4; ++i)
                #pragma unroll
                for (int j = 0; j < 4; ++j)
                    acc[i][j] = __builtin_amdgcn_mfma_f32_16x16x32_bf16(af[i], bfr[j], acc[i][j], 0, 0, 0);
        }
        __syncthreads();
    }
    #pragma unroll
    for (int i = 0; i < 4; ++i){
        #pragma unroll
        for (int r = 0; r < 4; ++r){
            const int s = s0 + wm + i*16 + quad*4 + r;
            #pragma unroll
            for (int j = 0; j < 4; ++j){
                const int n = n0 + wn + j*16 + l15;
                C[(size_t)s*DD + n] = f2bfbits(acc[i][j][r]);
            }
        }
    }
}

extern "C" void kernel_launch(void* const* d_in, const int* in_sizes, int n_in,
                              void* d_out, int out_size, void* d_ws, size_t ws_size,
                              hipStream_t stream)
{
    (void)in_sizes; (void)n_in; (void)out_size;
    const float* x   = (const float*)d_in[0];
    const float* bq  = (const float*)d_in[2];
    const float* bk  = (const float*)d_in[4];
    const float* bv  = (const float*)d_in[6];
    const float* bo  = (const float*)d_in[8];
    const float* b1  = (const float*)d_in[10];
    const float* b2  = (const float*)d_in[12];
    const float* g1  = (const float*)d_in[13];
    const float* be1 = (const float*)d_in[14];
    const float* g2  = (const float*)d_in[15];
    const float* be2 = (const float*)d_in[16];
    float* outf = (float*)d_out;

    if (ws_size < (size_t)REQ_WS){
        sentinel_kernel<<<dim3((unsigned)(MD/256)), dim3(256), 0, stream>>>(outf, 1.0e9f);
        return;
    }

    unsigned short* wsb = (unsigned short*)d_ws;
    unsigned short* Qw  = wsb;                 // -> ctx
    unsigned short* Kw  = wsb + MD;            // \ -> Hf (fp32 spans K+VT)
    unsigned short* VTw = wsb + 2*MD;          // /
    unsigned short* Pw  = wsb + 3*MD;          // packed P -> mid
    unsigned short* WT  = wsb + WT_OFF;
    unsigned short* ZP  = wsb + ZP_OFF;
    float*          Hf  = (float*)Kw;
    unsigned short* CTX = Qw;
    unsigned short* MIDw= Pw;
    unsigned short* LN  = (unsigned short*)d_out;   // LN1/LN2 scratch in d_out

    WPack wp;
    static const int widx[6] = {1,3,5,7,9,11};
    for (int i = 0; i < 6; ++i){
        wp.w[i] = (const float*)d_in[widx[i]];
        wp.o[i] = WT + (size_t)i*DD*DD;
    }
    wp.zp = ZP;
    unsigned short* WqT = wp.o[0]; unsigned short* WkT = wp.o[1];
    unsigned short* WvT = wp.o[2]; unsigned short* WoT = wp.o[3];
    unsigned short* W1T = wp.o[4]; unsigned short* W2T = wp.o[5];

    const dim3 blk(256);
    const float scale = 1.0f / sqrtf((float)SS);
    const dim3 gA(DD/128, MM/128);    // (8,64)
    const dim3 gVT(MM/128, DD/128);   // (64,8)

    wtrans<<<dim3(16,16,6), blk, 0, stream>>>(wp);
    ln_f32<<<dim3(MM), blk, 0, stream>>>(x, g1, be1, LN);
    // Q,K merged (1024 blocks)
    gemm_qk<<<dim3(DD/128, MM/128, 2), blk, 0, stream>>>(LN, WqT, WkT, bq, bk, Qw, Kw);
    // VT[d][tok] = WvT . LN^T (bias along m)
    gemm_mfma<false,false,false,true ><<<gVT, blk, 0, stream>>>(WvT, LN, bv, nullptr, VTw, nullptr, MM, DD, DD, DD);
    // attention
    scores_mfma<<<dim3(SS/128, SS/128, BB), blk, 0, stream>>>(Qw, Kw, Pw, scale);
    softmax_p<<<dim3(SS, BB), blk, 0, stream>>>(Pw);
    pv_mfma<<<dim3(DD/128, SS/128, BB), blk, 0, stream>>>(Pw, VTw, CTX, ZP);
    // h = ctx*WoT^T + bo + x (fp32)
    gemm_mfma<false,true,true,false><<<gA, blk, 0, stream>>>(CTX, WoT, bo, x, nullptr, Hf, DD, DD, DD, DD);
    ln_f32<<<dim3(MM), blk, 0, stream>>>(Hf, g2, be2, LN);
    // mid = relu(LN*W1T^T + b1)
    gemm_mfma<true,false,false,false><<<gA, blk, 0, stream>>>(LN, W1T, b1, nullptr, MIDw, nullptr, DD, DD, DD, DD);
    // out = mid*W2T^T + b2 + h
    gemm_mfma<false,true,true,false><<<gA, blk, 0, stream>>>(MIDw, W2T, b2, Hf, nullptr, outf, DD, DD, DD, DD);
}